// Round 1
// baseline (18801.349 us; speedup 1.0000x reference)
//
#include <hip/hip_runtime.h>
#include <hip/hip_bf16.h>
#include <math.h>

#define V 10000
#define E 512
#define H 1024
#define LAYERS 2
#define T 128
#define B 64
#define KK 128   // k-chunk staged in LDS for stage kernels

// ---------------------------------------------------------------------------
// Generic fp32 GEMM:  C[m, n+coff] = sum_k A[arow(m)*lda + k] * Bm[n*ldb + k] (+bias[n])
// A row-major [M, K] (optionally gathered via rowidx), Bm row-major [N, K].
// BM=BN=128, BK=8, 256 threads, 8x8 register tile.
// ---------------------------------------------------------------------------
__global__ __launch_bounds__(256) void gemm_tn(
    const float* __restrict__ A, const float* __restrict__ Bm,
    const float* __restrict__ bias, float* __restrict__ C,
    const int* __restrict__ rowidx,
    int M, int N, int K, int lda, int ldb, int ldc, int coff)
{
    __shared__ float As[8][128 + 4];
    __shared__ float Bs[8][128 + 4];
    const int t  = threadIdx.x;
    const int bn = blockIdx.x * 128;
    const int bm = blockIdx.y * 128;
    const int tx = t % 16, ty = t / 16;
    const int lrow = t / 2, lkq = t % 2;

    const int am = bm + lrow;
    const int arow = (am < M) ? (rowidx ? rowidx[am] : am) : 0;
    const int brow = bn + lrow;

    float acc[8][8];
    #pragma unroll
    for (int i = 0; i < 8; ++i)
        #pragma unroll
        for (int j = 0; j < 8; ++j) acc[i][j] = 0.f;

    for (int k0 = 0; k0 < K; k0 += 8) {
        float4 va = {0, 0, 0, 0};
        if (am < M) va = *(const float4*)(A + (size_t)arow * lda + k0 + 4 * lkq);
        float4 vb = {0, 0, 0, 0};
        if (brow < N) vb = *(const float4*)(Bm + (size_t)brow * ldb + k0 + 4 * lkq);
        As[4 * lkq + 0][lrow] = va.x; As[4 * lkq + 1][lrow] = va.y;
        As[4 * lkq + 2][lrow] = va.z; As[4 * lkq + 3][lrow] = va.w;
        Bs[4 * lkq + 0][lrow] = vb.x; Bs[4 * lkq + 1][lrow] = vb.y;
        Bs[4 * lkq + 2][lrow] = vb.z; Bs[4 * lkq + 3][lrow] = vb.w;
        __syncthreads();
        #pragma unroll
        for (int k = 0; k < 8; ++k) {
            float a[8], b[8];
            *(float4*)&a[0] = *(const float4*)&As[k][ty * 8];
            *(float4*)&a[4] = *(const float4*)&As[k][ty * 8 + 4];
            *(float4*)&b[0] = *(const float4*)&Bs[k][tx * 8];
            *(float4*)&b[4] = *(const float4*)&Bs[k][tx * 8 + 4];
            #pragma unroll
            for (int i = 0; i < 8; ++i)
                #pragma unroll
                for (int j = 0; j < 8; ++j)
                    acc[i][j] = fmaf(a[i], b[j], acc[i][j]);
        }
        __syncthreads();
    }

    #pragma unroll
    for (int i = 0; i < 8; ++i) {
        int m = bm + ty * 8 + i;
        if (m >= M) continue;
        #pragma unroll
        for (int j = 0; j < 8; ++j) {
            int n = bn + tx * 8 + j;
            if (n >= N) continue;
            float v = acc[i][j];
            if (bias) v += bias[n];
            C[(size_t)m * ldc + n + coff] = v;
        }
    }
}

// ---------------------------------------------------------------------------
// init: hidden [L][B][H] -> hT_l [H][B] (transposed)
// ---------------------------------------------------------------------------
__global__ __launch_bounds__(256) void init_hT(
    const float* __restrict__ hidden, float* __restrict__ hT0, float* __restrict__ hT1)
{
    int idx = blockIdx.x * 256 + threadIdx.x;        // 0 .. 2*B*H-1
    int l = idx / (B * H);
    int r = idx % (B * H);
    int b = r / H, k = r % H;
    float v = hidden[idx];
    float* dst = (l == 0) ? hT0 : hT1;
    dst[k * B + b] = v;
}

// ---------------------------------------------------------------------------
// h_final: hT_l [H][B] -> out [L][B][H]
// ---------------------------------------------------------------------------
__global__ __launch_bounds__(256) void write_hfinal(
    const float* __restrict__ hT0, const float* __restrict__ hT1, float* __restrict__ outp)
{
    int idx = blockIdx.x * 256 + threadIdx.x;        // 0 .. 2*B*H-1
    int l = idx / (B * H);
    int r = idx % (B * H);
    int b = r / H, k = r % H;
    const float* src = (l == 0) ? hT0 : hT1;
    outp[idx] = src[k * B + b];
}

// ---------------------------------------------------------------------------
// Stage 1: rz = sigmoid(Wx_rz + h @ [Ur;Uz]^T); writes rhT = r*h and zT.
// Grid: 2H/16 = 128 blocks, 256 threads (4 waves), 4 cols/wave, lane = b.
// hT layout [H][B]; LDS-staged in KK-chunks (contiguous copy).
// ---------------------------------------------------------------------------
__global__ __launch_bounds__(256) void gru_stage1(
    const float* __restrict__ hT, const float* __restrict__ Ur,
    const float* __restrict__ Uz, const float* __restrict__ Wx,
    float* __restrict__ rhT, float* __restrict__ zT, int t)
{
    __shared__ float hs[KK * B];
    const int tid  = threadIdx.x;
    const int lane = tid & 63;
    const int wv   = __builtin_amdgcn_readfirstlane(tid >> 6);
    const int jblk = blockIdx.x * 16;                   // [0, 2048)
    const float* __restrict__ U = (jblk < H) ? (Ur + (size_t)jblk * H)
                                             : (Uz + (size_t)(jblk - H) * H);
    const int lj = wv * 4;
    float acc[4] = {0.f, 0.f, 0.f, 0.f};

    for (int k0 = 0; k0 < H; k0 += KK) {
        __syncthreads();
        const float4* src = (const float4*)(hT + (size_t)k0 * B);
        float4* dst = (float4*)hs;
        #pragma unroll
        for (int i = 0; i < (KK * B / 4) / 256; ++i)
            dst[tid + i * 256] = src[tid + i * 256];
        __syncthreads();
        const float* __restrict__ u0 = U + (size_t)(lj + 0) * H + k0;
        const float* __restrict__ u1 = U + (size_t)(lj + 1) * H + k0;
        const float* __restrict__ u2 = U + (size_t)(lj + 2) * H + k0;
        const float* __restrict__ u3 = U + (size_t)(lj + 3) * H + k0;
        #pragma unroll 8
        for (int k = 0; k < KK; ++k) {
            float hk = hs[k * B + lane];
            acc[0] = fmaf(hk, u0[k], acc[0]);
            acc[1] = fmaf(hk, u1[k], acc[1]);
            acc[2] = fmaf(hk, u2[k], acc[2]);
            acc[3] = fmaf(hk, u3[k], acc[3]);
        }
    }

    const size_t wxrow = ((size_t)t * B + lane) * (3 * H);
    #pragma unroll
    for (int jj = 0; jj < 4; ++jj) {
        int j = jblk + lj + jj;
        float val = acc[jj] + Wx[wxrow + j];
        float g = 1.f / (1.f + __expf(-val));
        if (j < H) rhT[(size_t)j * B + lane] = g * hT[(size_t)j * B + lane];
        else       zT[(size_t)(j - H) * B + lane] = g;
    }
}

// ---------------------------------------------------------------------------
// Stage 2: h~ = tanh(Wx_h + (r*h) @ Uh^T); h = (1-z)h + z h~.
// Grid: H/8 = 128 blocks, 256 threads, 2 cols/wave.
// Writes hT in place and hseqT[t].
// ---------------------------------------------------------------------------
__global__ __launch_bounds__(256) void gru_stage2(
    const float* __restrict__ rhT, const float* __restrict__ Uh,
    const float* __restrict__ Wx, const float* __restrict__ zT,
    float* __restrict__ hT, float* __restrict__ hseqT, int t)
{
    __shared__ float hs[KK * B];
    const int tid  = threadIdx.x;
    const int lane = tid & 63;
    const int wv   = __builtin_amdgcn_readfirstlane(tid >> 6);
    const int jblk = blockIdx.x * 8;                    // [0, 1024)
    const float* __restrict__ U = Uh + (size_t)jblk * H;
    const int lj = wv * 2;
    float acc[2] = {0.f, 0.f};

    for (int k0 = 0; k0 < H; k0 += KK) {
        __syncthreads();
        const float4* src = (const float4*)(rhT + (size_t)k0 * B);
        float4* dst = (float4*)hs;
        #pragma unroll
        for (int i = 0; i < (KK * B / 4) / 256; ++i)
            dst[tid + i * 256] = src[tid + i * 256];
        __syncthreads();
        const float* __restrict__ u0 = U + (size_t)(lj + 0) * H + k0;
        const float* __restrict__ u1 = U + (size_t)(lj + 1) * H + k0;
        #pragma unroll 8
        for (int k = 0; k < KK; ++k) {
            float hk = hs[k * B + lane];
            acc[0] = fmaf(hk, u0[k], acc[0]);
            acc[1] = fmaf(hk, u1[k], acc[1]);
        }
    }

    const size_t wxrow = ((size_t)t * B + lane) * (3 * H) + 2 * H;
    #pragma unroll
    for (int jj = 0; jj < 2; ++jj) {
        int j = jblk + lj + jj;
        float val = acc[jj] + Wx[wxrow + j];
        float htl = tanhf(val);
        float z    = zT[(size_t)j * B + lane];
        float hold = hT[(size_t)j * B + lane];
        float hnew = (1.f - z) * hold + z * htl;
        hT[(size_t)j * B + lane] = hnew;
        hseqT[(size_t)t * H * B + (size_t)j * B + lane] = hnew;
    }
}

// ---------------------------------------------------------------------------
// Transpose per-timestep: in [T][H][B] -> out [T*B][H]
// grid (H/64, T), 256 threads
// ---------------------------------------------------------------------------
__global__ __launch_bounds__(256) void transpose_TqB(
    const float* __restrict__ in, float* __restrict__ out)
{
    __shared__ float tile[64][65];
    const int t  = blockIdx.y;
    const int k0 = blockIdx.x * 64;
    const int tx = threadIdx.x % 64, ty = threadIdx.x / 64;   // ty 0..3
    const float* src = in + (size_t)t * H * B + (size_t)k0 * B;
    #pragma unroll
    for (int r = 0; r < 16; ++r) {
        int k = r * 4 + ty;
        tile[k][tx] = src[(size_t)k * B + tx];
    }
    __syncthreads();
    float* dst = out + (size_t)t * B * H + k0;
    #pragma unroll
    for (int r = 0; r < 16; ++r) {
        int b = r * 4 + ty;
        dst[(size_t)b * H + tx] = tile[tx][b];
    }
}

// ---------------------------------------------------------------------------
extern "C" void kernel_launch(void* const* d_in, const int* in_sizes, int n_in,
                              void* d_out, int out_size, void* d_ws, size_t ws_size,
                              hipStream_t stream)
{
    const int*   tok    = (const int*)d_in[0];
    const float* hidden = (const float*)d_in[1];
    const float* emb    = (const float*)d_in[2];
    const float* Wr0 = (const float*)d_in[3],  *br0 = (const float*)d_in[4];
    const float* Wz0 = (const float*)d_in[5],  *bz0 = (const float*)d_in[6];
    const float* Wh0 = (const float*)d_in[7],  *bh0 = (const float*)d_in[8];
    const float* Ur0 = (const float*)d_in[9],  *Uz0 = (const float*)d_in[10], *Uh0 = (const float*)d_in[11];
    const float* Wr1 = (const float*)d_in[12], *br1 = (const float*)d_in[13];
    const float* Wz1 = (const float*)d_in[14], *bz1 = (const float*)d_in[15];
    const float* Wh1 = (const float*)d_in[16], *bh1 = (const float*)d_in[17];
    const float* Ur1 = (const float*)d_in[18], *Uz1 = (const float*)d_in[19], *Uh1 = (const float*)d_in[20];
    const float* Wout = (const float*)d_in[21], *bout = (const float*)d_in[22];
    float* out = (float*)d_out;

    float* ws   = (float*)d_ws;
    float* Wx   = ws;                                  // T*B*3H = 25,165,824 f
    float* bufT = Wx   + (size_t)T * B * 3 * H;        // 8,388,608 f  (hseq transposed)
    float* bufS = bufT + (size_t)T * H * B;            // 8,388,608 f  (hseq row-major)
    float* hT0  = bufS + (size_t)T * B * H;            // 65,536 f
    float* hT1  = hT0 + B * H;
    float* rhT  = hT1 + B * H;
    float* zTb  = rhT + B * H;

    init_hT<<<(2 * B * H) / 256, 256, 0, stream>>>(hidden, hT0, hT1);

    // ---- layer 0: Wx = emb[tok] @ [Wr;Wz;Wh]^T + b  (gather fused via rowidx)
    gemm_tn<<<dim3(H / 128, T * B / 128), 256, 0, stream>>>(emb, Wr0, br0, Wx, tok, T * B, H, E, E, E, 3 * H, 0);
    gemm_tn<<<dim3(H / 128, T * B / 128), 256, 0, stream>>>(emb, Wz0, bz0, Wx, tok, T * B, H, E, E, E, 3 * H, H);
    gemm_tn<<<dim3(H / 128, T * B / 128), 256, 0, stream>>>(emb, Wh0, bh0, Wx, tok, T * B, H, E, E, E, 3 * H, 2 * H);

    for (int t = 0; t < T; ++t) {
        gru_stage1<<<128, 256, 0, stream>>>(hT0, Ur0, Uz0, Wx, rhT, zTb, t);
        gru_stage2<<<128, 256, 0, stream>>>(rhT, Uh0, Wx, zTb, hT0, bufT, t);
    }
    transpose_TqB<<<dim3(H / 64, T), 256, 0, stream>>>(bufT, bufS);

    // ---- layer 1: Wx = hseq0 @ [Wr1;Wz1;Wh1]^T + b
    gemm_tn<<<dim3(H / 128, T * B / 128), 256, 0, stream>>>(bufS, Wr1, br1, Wx, nullptr, T * B, H, H, H, H, 3 * H, 0);
    gemm_tn<<<dim3(H / 128, T * B / 128), 256, 0, stream>>>(bufS, Wz1, bz1, Wx, nullptr, T * B, H, H, H, H, 3 * H, H);
    gemm_tn<<<dim3(H / 128, T * B / 128), 256, 0, stream>>>(bufS, Wh1, bh1, Wx, nullptr, T * B, H, H, H, H, 3 * H, 2 * H);

    for (int t = 0; t < T; ++t) {
        gru_stage1<<<128, 256, 0, stream>>>(hT1, Ur1, Uz1, Wx, rhT, zTb, t);
        gru_stage2<<<128, 256, 0, stream>>>(rhT, Uh1, Wx, zTb, hT1, bufT, t);
    }
    transpose_TqB<<<dim3(H / 64, T), 256, 0, stream>>>(bufT, bufS);

    // ---- logits = hseq1 @ Wout^T + bout
    gemm_tn<<<dim3((V + 127) / 128, T * B / 128), 256, 0, stream>>>(bufS, Wout, bout, out, nullptr, T * B, V, H, H, H, V, 0);

    // ---- h_final
    write_hfinal<<<(2 * B * H) / 256, 256, 0, stream>>>(hT0, hT1, out + (size_t)T * B * V);
}

// Round 2
// 13537.863 us; speedup vs baseline: 1.3888x; 1.3888x over previous
//
#include <hip/hip_runtime.h>
#include <hip/hip_bf16.h>
#include <math.h>

#define V 10000
#define E 512
#define H 1024
#define LAYERS 2
#define T 128
#define B 64
#define KK 128   // k-chunk staged in LDS for stage kernels

typedef __bf16 bf16x8 __attribute__((ext_vector_type(8)));
typedef float f32x4 __attribute__((ext_vector_type(4)));
typedef unsigned short ushort8 __attribute__((ext_vector_type(8)));

// Split-pack 4 fp32 into 4 truncated-hi bf16 and 4 residual-lo bf16 (packed u32 pairs).
// x = hi + lo with |err| <= 2^-16 |x|  (hi truncated, lo = bf16-trunc(x - hi)).
__device__ inline void splitpack(float4 v, uint2& hi, uint2& lo) {
    unsigned u0 = __float_as_uint(v.x), u1 = __float_as_uint(v.y);
    unsigned u2 = __float_as_uint(v.z), u3 = __float_as_uint(v.w);
    hi.x = __builtin_amdgcn_perm(u1, u0, 0x07060302u);
    hi.y = __builtin_amdgcn_perm(u3, u2, 0x07060302u);
    float l0 = v.x - __uint_as_float(u0 & 0xFFFF0000u);
    float l1 = v.y - __uint_as_float(u1 & 0xFFFF0000u);
    float l2 = v.z - __uint_as_float(u2 & 0xFFFF0000u);
    float l3 = v.w - __uint_as_float(u3 & 0xFFFF0000u);
    lo.x = __builtin_amdgcn_perm(__float_as_uint(l1), __float_as_uint(l0), 0x07060302u);
    lo.y = __builtin_amdgcn_perm(__float_as_uint(l3), __float_as_uint(l2), 0x07060302u);
}

// ---------------------------------------------------------------------------
// Split-bf16 MFMA GEMM: C[m, n+coff] = sum_k A[row(m)][k] * W[n][k] (+bias[n])
// A fp32 row-major [M,K] (optional gather), W fp32 row-major [N,K].
// 128x128 tile, BK=32, 256 threads (4 waves), 16x16x32 bf16 MFMA, 3-term split.
// Requires M % 128 == 0, K % 32 == 0. N arbitrary.
// ---------------------------------------------------------------------------
__global__ __launch_bounds__(256) void gemm_mfma_split(
    const float* __restrict__ A, const float* __restrict__ W,
    const float* __restrict__ bias, float* __restrict__ C,
    const int* __restrict__ rowidx,
    int M, int N, int K, int lda, int ldb, int ldc, int coff)
{
    __shared__ __align__(16) unsigned short Ah[128 * 40];
    __shared__ __align__(16) unsigned short Al[128 * 40];
    __shared__ __align__(16) unsigned short Bh[128 * 40];
    __shared__ __align__(16) unsigned short Bl[128 * 40];

    const int tid  = threadIdx.x;
    const int lane = tid & 63;
    const int wv   = tid >> 6;
    const int wm   = wv & 1, wn = wv >> 1;
    const int bn = blockIdx.x * 128;
    const int bm = blockIdx.y * 128;

    // staging pointers (4 float4 per thread per operand per K-tile)
    const float* apt[4];
    const float* bpt[4];
    bool bok[4];
    unsigned lofs[4];
    #pragma unroll
    for (int i = 0; i < 4; ++i) {
        int f4 = i * 256 + tid, r = f4 >> 3, kq = f4 & 7;
        int gm = bm + r;
        int ar = rowidx ? rowidx[gm] : gm;
        apt[i] = A + (size_t)ar * lda + kq * 4;
        int gn = bn + r;
        bok[i] = (gn < N);
        bpt[i] = W + (size_t)(bok[i] ? gn : 0) * ldb + kq * 4;
        lofs[i] = r * 40 + kq * 4;
    }

    f32x4 acc[4][4];
    #pragma unroll
    for (int i = 0; i < 4; ++i)
        #pragma unroll
        for (int j = 0; j < 4; ++j) acc[i][j] = (f32x4){0.f, 0.f, 0.f, 0.f};

    const int la  = lane & 15;
    const int kg8 = (lane >> 4) * 8;

    for (int k0 = 0; k0 < K; k0 += 32) {
        __syncthreads();
        #pragma unroll
        for (int i = 0; i < 4; ++i) {
            float4 va = *(const float4*)(apt[i] + k0);
            uint2 h, l;
            splitpack(va, h, l);
            *(uint2*)&Ah[lofs[i]] = h;
            *(uint2*)&Al[lofs[i]] = l;
            float4 vb = {0.f, 0.f, 0.f, 0.f};
            if (bok[i]) vb = *(const float4*)(bpt[i] + k0);
            splitpack(vb, h, l);
            *(uint2*)&Bh[lofs[i]] = h;
            *(uint2*)&Bl[lofs[i]] = l;
        }
        __syncthreads();

        bf16x8 ah[4], al[4];
        #pragma unroll
        for (int mt = 0; mt < 4; ++mt) {
            int row = (wm * 64 + mt * 16 + la) * 40 + kg8;
            ah[mt] = __builtin_bit_cast(bf16x8, *(const ushort8*)&Ah[row]);
            al[mt] = __builtin_bit_cast(bf16x8, *(const ushort8*)&Al[row]);
        }
        #pragma unroll
        for (int nt = 0; nt < 4; ++nt) {
            int row = (wn * 64 + nt * 16 + la) * 40 + kg8;
            bf16x8 bh = __builtin_bit_cast(bf16x8, *(const ushort8*)&Bh[row]);
            bf16x8 bl = __builtin_bit_cast(bf16x8, *(const ushort8*)&Bl[row]);
            #pragma unroll
            for (int mt = 0; mt < 4; ++mt) {
                acc[mt][nt] = __builtin_amdgcn_mfma_f32_16x16x32_bf16(ah[mt], bh, acc[mt][nt], 0, 0, 0);
                acc[mt][nt] = __builtin_amdgcn_mfma_f32_16x16x32_bf16(al[mt], bh, acc[mt][nt], 0, 0, 0);
                acc[mt][nt] = __builtin_amdgcn_mfma_f32_16x16x32_bf16(ah[mt], bl, acc[mt][nt], 0, 0, 0);
            }
        }
    }

    // epilogue: C/D layout col = lane&15, row = (lane>>4)*4 + reg
    #pragma unroll
    for (int mt = 0; mt < 4; ++mt) {
        int mrow = bm + wm * 64 + mt * 16 + (lane >> 4) * 4;
        #pragma unroll
        for (int nt = 0; nt < 4; ++nt) {
            int n = bn + wn * 64 + nt * 16 + la;
            if (n < N) {
                float bi = bias ? bias[n] : 0.f;
                #pragma unroll
                for (int r = 0; r < 4; ++r)
                    C[(size_t)(mrow + r) * ldc + n + coff] = acc[mt][nt][r] + bi;
            }
        }
    }
}

// ---------------------------------------------------------------------------
// init: hidden [L][B][H] -> hT_l [H][B] (transposed)
// ---------------------------------------------------------------------------
__global__ __launch_bounds__(256) void init_hT(
    const float* __restrict__ hidden, float* __restrict__ hT0, float* __restrict__ hT1)
{
    int idx = blockIdx.x * 256 + threadIdx.x;
    int l = idx / (B * H);
    int r = idx % (B * H);
    int b = r / H, k = r % H;
    float v = hidden[idx];
    float* dst = (l == 0) ? hT0 : hT1;
    dst[k * B + b] = v;
}

__global__ __launch_bounds__(256) void write_hfinal(
    const float* __restrict__ hT0, const float* __restrict__ hT1, float* __restrict__ outp)
{
    int idx = blockIdx.x * 256 + threadIdx.x;
    int l = idx / (B * H);
    int r = idx % (B * H);
    int b = r / H, k = r % H;
    const float* src = (l == 0) ? hT0 : hT1;
    outp[idx] = src[k * B + b];
}

// ---------------------------------------------------------------------------
// Stage 1: rz = sigmoid(Wx_rz + h @ [Ur;Uz]^T); writes rhT = r*h and zT.
// Grid: 256 blocks x 256 threads (4 waves), 2 cols/wave, lane = b.
// ---------------------------------------------------------------------------
__global__ __launch_bounds__(256) void gru_stage1(
    const float* __restrict__ hT, const float* __restrict__ Ur,
    const float* __restrict__ Uz, const float* __restrict__ Wx,
    float* __restrict__ rhT, float* __restrict__ zT, int t)
{
    __shared__ float hs[KK * B];
    const int tid  = threadIdx.x;
    const int lane = tid & 63;
    const int wv   = __builtin_amdgcn_readfirstlane(tid >> 6);
    const int jblk = blockIdx.x * 8;                    // [0, 2048)
    const float* __restrict__ U = (jblk < H) ? (Ur + (size_t)jblk * H)
                                             : (Uz + (size_t)(jblk - H) * H);
    const int lj = wv * 2;
    float acc[2] = {0.f, 0.f};

    for (int k0 = 0; k0 < H; k0 += KK) {
        __syncthreads();
        const float4* src = (const float4*)(hT + (size_t)k0 * B);
        float4* dst = (float4*)hs;
        #pragma unroll
        for (int i = 0; i < (KK * B / 4) / 256; ++i)
            dst[tid + i * 256] = src[tid + i * 256];
        __syncthreads();
        const float* __restrict__ u0 = U + (size_t)(lj + 0) * H + k0;
        const float* __restrict__ u1 = U + (size_t)(lj + 1) * H + k0;
        #pragma unroll 8
        for (int k = 0; k < KK; ++k) {
            float hk = hs[k * B + lane];
            acc[0] = fmaf(hk, u0[k], acc[0]);
            acc[1] = fmaf(hk, u1[k], acc[1]);
        }
    }

    const size_t wxrow = ((size_t)t * B + lane) * (3 * H);
    #pragma unroll
    for (int jj = 0; jj < 2; ++jj) {
        int j = jblk + lj + jj;
        float val = acc[jj] + Wx[wxrow + j];
        float g = 1.f / (1.f + __expf(-val));
        if (j < H) rhT[(size_t)j * B + lane] = g * hT[(size_t)j * B + lane];
        else       zT[(size_t)(j - H) * B + lane] = g;
    }
}

// ---------------------------------------------------------------------------
// Stage 2: h~ = tanh(Wx_h + (r*h) @ Uh^T); h = (1-z)h + z h~.
// Grid: 256 blocks x 128 threads (2 waves), 2 cols/wave.
// ---------------------------------------------------------------------------
__global__ __launch_bounds__(128) void gru_stage2(
    const float* __restrict__ rhT, const float* __restrict__ Uh,
    const float* __restrict__ Wx, const float* __restrict__ zT,
    float* __restrict__ hT, float* __restrict__ hseqT, int t)
{
    __shared__ float hs[KK * B];
    const int tid  = threadIdx.x;
    const int lane = tid & 63;
    const int wv   = __builtin_amdgcn_readfirstlane(tid >> 6);
    const int jblk = blockIdx.x * 4;                    // [0, 1024)
    const float* __restrict__ U = Uh + (size_t)jblk * H;
    const int lj = wv * 2;
    float acc[2] = {0.f, 0.f};

    for (int k0 = 0; k0 < H; k0 += KK) {
        __syncthreads();
        const float4* src = (const float4*)(rhT + (size_t)k0 * B);
        float4* dst = (float4*)hs;
        #pragma unroll
        for (int i = 0; i < (KK * B / 4) / 128; ++i)
            dst[tid + i * 128] = src[tid + i * 128];
        __syncthreads();
        const float* __restrict__ u0 = U + (size_t)(lj + 0) * H + k0;
        const float* __restrict__ u1 = U + (size_t)(lj + 1) * H + k0;
        #pragma unroll 8
        for (int k = 0; k < KK; ++k) {
            float hk = hs[k * B + lane];
            acc[0] = fmaf(hk, u0[k], acc[0]);
            acc[1] = fmaf(hk, u1[k], acc[1]);
        }
    }

    const size_t wxrow = ((size_t)t * B + lane) * (3 * H) + 2 * H;
    #pragma unroll
    for (int jj = 0; jj < 2; ++jj) {
        int j = jblk + lj + jj;
        float val = acc[jj] + Wx[wxrow + j];
        float htl = tanhf(val);
        float z    = zT[(size_t)j * B + lane];
        float hold = hT[(size_t)j * B + lane];
        float hnew = (1.f - z) * hold + z * htl;
        hT[(size_t)j * B + lane] = hnew;
        hseqT[(size_t)t * H * B + (size_t)j * B + lane] = hnew;
    }
}

// ---------------------------------------------------------------------------
// Transpose per-timestep: in [T][H][B] -> out [T*B][H]
// ---------------------------------------------------------------------------
__global__ __launch_bounds__(256) void transpose_TqB(
    const float* __restrict__ in, float* __restrict__ out)
{
    __shared__ float tile[64][65];
    const int t  = blockIdx.y;
    const int k0 = blockIdx.x * 64;
    const int tx = threadIdx.x % 64, ty = threadIdx.x / 64;
    const float* src = in + (size_t)t * H * B + (size_t)k0 * B;
    #pragma unroll
    for (int r = 0; r < 16; ++r) {
        int k = r * 4 + ty;
        tile[k][tx] = src[(size_t)k * B + tx];
    }
    __syncthreads();
    float* dst = out + (size_t)t * B * H + k0;
    #pragma unroll
    for (int r = 0; r < 16; ++r) {
        int b = r * 4 + ty;
        dst[(size_t)b * H + tx] = tile[tx][b];
    }
}

// ---------------------------------------------------------------------------
extern "C" void kernel_launch(void* const* d_in, const int* in_sizes, int n_in,
                              void* d_out, int out_size, void* d_ws, size_t ws_size,
                              hipStream_t stream)
{
    const int*   tok    = (const int*)d_in[0];
    const float* hidden = (const float*)d_in[1];
    const float* emb    = (const float*)d_in[2];
    const float* Wr0 = (const float*)d_in[3],  *br0 = (const float*)d_in[4];
    const float* Wz0 = (const float*)d_in[5],  *bz0 = (const float*)d_in[6];
    const float* Wh0 = (const float*)d_in[7],  *bh0 = (const float*)d_in[8];
    const float* Ur0 = (const float*)d_in[9],  *Uz0 = (const float*)d_in[10], *Uh0 = (const float*)d_in[11];
    const float* Wr1 = (const float*)d_in[12], *br1 = (const float*)d_in[13];
    const float* Wz1 = (const float*)d_in[14], *bz1 = (const float*)d_in[15];
    const float* Wh1 = (const float*)d_in[16], *bh1 = (const float*)d_in[17];
    const float* Ur1 = (const float*)d_in[18], *Uz1 = (const float*)d_in[19], *Uh1 = (const float*)d_in[20];
    const float* Wout = (const float*)d_in[21], *bout = (const float*)d_in[22];
    float* out = (float*)d_out;

    float* ws   = (float*)d_ws;
    float* Wx   = ws;                                  // T*B*3H
    float* bufT = Wx   + (size_t)T * B * 3 * H;        // T*H*B (hseq transposed)
    float* bufS = bufT + (size_t)T * H * B;            // T*B*H (hseq row-major)
    float* hT0  = bufS + (size_t)T * B * H;
    float* hT1  = hT0 + B * H;
    float* rhT  = hT1 + B * H;
    float* zTb  = rhT + B * H;

    init_hT<<<(2 * B * H) / 256, 256, 0, stream>>>(hidden, hT0, hT1);

    // ---- layer 0: Wx = emb[tok] @ [Wr;Wz;Wh]^T + b  (gather fused)
    gemm_mfma_split<<<dim3(H / 128, T * B / 128), 256, 0, stream>>>(emb, Wr0, br0, Wx, tok, T * B, H, E, E, E, 3 * H, 0);
    gemm_mfma_split<<<dim3(H / 128, T * B / 128), 256, 0, stream>>>(emb, Wz0, bz0, Wx, tok, T * B, H, E, E, E, 3 * H, H);
    gemm_mfma_split<<<dim3(H / 128, T * B / 128), 256, 0, stream>>>(emb, Wh0, bh0, Wx, tok, T * B, H, E, E, E, 3 * H, 2 * H);

    for (int t = 0; t < T; ++t) {
        gru_stage1<<<256, 256, 0, stream>>>(hT0, Ur0, Uz0, Wx, rhT, zTb, t);
        gru_stage2<<<256, 128, 0, stream>>>(rhT, Uh0, Wx, zTb, hT0, bufT, t);
    }
    transpose_TqB<<<dim3(H / 64, T), 256, 0, stream>>>(bufT, bufS);

    // ---- layer 1: Wx = hseq0 @ [Wr1;Wz1;Wh1]^T + b
    gemm_mfma_split<<<dim3(H / 128, T * B / 128), 256, 0, stream>>>(bufS, Wr1, br1, Wx, nullptr, T * B, H, H, H, H, 3 * H, 0);
    gemm_mfma_split<<<dim3(H / 128, T * B / 128), 256, 0, stream>>>(bufS, Wz1, bz1, Wx, nullptr, T * B, H, H, H, H, 3 * H, H);
    gemm_mfma_split<<<dim3(H / 128, T * B / 128), 256, 0, stream>>>(bufS, Wh1, bh1, Wx, nullptr, T * B, H, H, H, H, 3 * H, 2 * H);

    for (int t = 0; t < T; ++t) {
        gru_stage1<<<256, 256, 0, stream>>>(hT1, Ur1, Uz1, Wx, rhT, zTb, t);
        gru_stage2<<<256, 128, 0, stream>>>(rhT, Uh1, Wx, zTb, hT1, bufT, t);
    }
    transpose_TqB<<<dim3(H / 64, T), 256, 0, stream>>>(bufT, bufS);

    // ---- logits = hseq1 @ Wout^T + bout
    gemm_mfma_split<<<dim3((V + 127) / 128, T * B / 128), 256, 0, stream>>>(bufS, Wout, bout, out, nullptr, T * B, V, H, H, H, V, 0);

    // ---- h_final
    write_hfinal<<<(2 * B * H) / 256, 256, 0, stream>>>(hT0, hT1, out + (size_t)T * B * V);
}